// Round 8
// baseline (364.484 us; speedup 1.0000x reference)
//
#include <hip/hip_runtime.h>

#define TSEQ 2048
#define KDIM 1024
#define NHEAD 16
#define HDIM 64
#define BATCH 4
#define HALF 512

typedef __attribute__((ext_vector_type(4))) float f32x4;
typedef __attribute__((ext_vector_type(16))) float f32x16;
typedef __attribute__((ext_vector_type(8))) short short8;
typedef __attribute__((ext_vector_type(4))) unsigned short us4;
typedef __attribute__((ext_vector_type(4))) unsigned int u32x4;

#if __has_builtin(__builtin_amdgcn_exp2f)
#define EXP2(x) __builtin_amdgcn_exp2f(x)
#else
#define EXP2(x) __expf((x)*0.6931471805599453f)
#endif

__device__ __forceinline__ unsigned short f2bf(float f){
  unsigned int u = __float_as_uint(f);
  u += 0x7FFFu + ((u >> 16) & 1u);   // round-to-nearest-even
  return (unsigned short)(u >> 16);
}

__device__ __forceinline__ unsigned int cvtpk(float a, float b){
  unsigned int r;
  asm("v_cvt_pk_bf16_f32 %0, %1, %2" : "=v"(r) : "v"(a), "v"(b));
  return r;   // lo = bf16(a), hi = bf16(b)
}

__device__ __forceinline__ f32x4 mfma16(short8 a, short8 b, f32x4 c){
  return __builtin_amdgcn_mfma_f32_16x16x32_bf16(a, b, c, 0, 0, 0);
}
__device__ __forceinline__ f32x16 mfma32(short8 a, short8 b, f32x16 c){
  return __builtin_amdgcn_mfma_f32_32x32x16_bf16(a, b, c, 0, 0, 0);
}

__device__ __forceinline__ void gl_lds16(const void* g, void* l){
  __builtin_amdgcn_global_load_lds(
      (const __attribute__((address_space(1))) unsigned int*)g,
      (__attribute__((address_space(3))) unsigned int*)l, 16, 0, 0);
}

// ---------------- fp32 -> bf16 convert (vectorized) ----------------
__global__ __launch_bounds__(256) void cvt_bf16(const float* __restrict__ in,
                                                unsigned short* __restrict__ out,
                                                int n4){
  int i = blockIdx.x*256 + threadIdx.x;
  if (i >= n4) return;
  f32x4 v = ((const f32x4*)in)[i];
  us4 o;
  o[0] = f2bf(v[0]); o[1] = f2bf(v[1]); o[2] = f2bf(v[2]); o[3] = f2bf(v[3]);
  ((us4*)out)[i] = o;
}

// ------------- RoPE cos/sin table, interleaved float2 [TSEQ][HALF] --------
__global__ __launch_bounds__(256) void trig_init(float2* __restrict__ csT){
  int idx = blockIdx.x*256 + threadIdx.x;   // TSEQ*HALF total
  int t = idx >> 9;
  int j = idx & (HALF-1);
  float theta = powf(10000.0f, -(float)j * (1.0f/(float)HALF));
  float ang = (float)t * theta;
  csT[idx] = make_float2(cosf(ang), sinf(ang));
}

// -------- fused QKV GEMM: C[m,n] = sum_k A[m,k]*B[n,k], 3 weight regions ----
// grid (64, 24). Row-chunked XCD swizzle: XCD k owns bx in [8k,8k+8), all 24
// column panels, by-fastest (A-tile stays L2-hot across its 24 uses).
// LDS tiles XOR-swizzled (granule cc' = cc ^ ((row>>1)&3)) via pre-swizzled
// global SOURCE (dest linear for global_load_lds) + swizzled ds_read col.
__global__ __launch_bounds__(256) void gemm_qkv(
    const unsigned short* __restrict__ A,
    const unsigned short* __restrict__ Wq,
    const unsigned short* __restrict__ Wk,
    const unsigned short* __restrict__ Wv,
    unsigned short* __restrict__ Qo,
    unsigned short* __restrict__ Ko,
    unsigned short* __restrict__ Vo,
    const float2* __restrict__ csT){
  __shared__ __align__(16) unsigned short As[128*32];
  __shared__ __align__(16) unsigned short Bs[128*32];
  const int lin = blockIdx.y*64 + blockIdx.x;
  const int L = (lin & 7)*192 + (lin >> 3);   // bijective: 1536 % 8 == 0
  const int bx = L/24, by = L%24;
  const int region = by >> 3;          // 0=Q 1=K 2=V
  const int tm = bx*128, tn = (by & 7)*128;
  const unsigned short* Bw = region==0 ? Wq : (region==1 ? Wk : Wv);
  unsigned short* outp     = region==0 ? Qo : (region==1 ? Ko : Vo);
  const float scale = (region==0) ? 0.18033688011112042f : 1.0f; // 0.125*log2e

  const int t  = threadIdx.x;
  const int w  = t>>6, l = t&63;
  const int wm = (w>>1)*64, wn = (w&1)*64;
  const int lr = l&15, g = l>>4, g4 = (l>>4)*4;

  f32x4 acc[4][4];
  #pragma unroll
  for (int i=0;i<4;i++)
    #pragma unroll
    for (int j=0;j<4;j++) acc[i][j] = (f32x4){0.f,0.f,0.f,0.f};

  // staging: thread t -> LDS granule (sr, cc); source col granule cc^swz(sr)
  const int sr = t>>2, cc = t&3;
  const int sc = (cc ^ ((sr>>1)&3))*8;     // swz(sr+64)==swz(sr)
  const unsigned short* Ag = A  + (size_t)(tm+sr)*KDIM + sc;
  const unsigned short* Bg = Bw + (size_t)(tn+sr)*KDIM + sc;
  unsigned short* Al0 = As + t*8;
  unsigned short* Al1 = As + 2048 + t*8;
  unsigned short* Bl0 = Bs + t*8;
  unsigned short* Bl1 = Bs + 2048 + t*8;

  for (int k0=0; k0<KDIM; k0+=32){
    gl_lds16(Ag + k0, Al0);
    gl_lds16(Ag + (size_t)64*KDIM + k0, Al1);
    gl_lds16(Bg + k0, Bl0);
    gl_lds16(Bg + (size_t)64*KDIM + k0, Bl1);
    __syncthreads();
    short8 af[4], bfr[4];
    #pragma unroll
    for (int i=0;i<4;i++){
      int ra = wm+i*16+lr, rb = wn+i*16+lr;
      af[i]  = *(const short8*)&As[ra*32 + (g ^ ((ra>>1)&3))*8];
      bfr[i] = *(const short8*)&Bs[rb*32 + (g ^ ((rb>>1)&3))*8];
    }
    #pragma unroll
    for (int i=0;i<4;i++)
      #pragma unroll
      for (int j=0;j<4;j++)
        acc[i][j] = mfma16(af[i], bfr[j], acc[i][j]);
    __syncthreads();
  }

  #pragma unroll
  for (int i=0;i<4;i++){
    #pragma unroll
    for (int j=0;j<4;j++){
      #pragma unroll
      for (int r=0;r<4;r++){
        int row = tm + wm + i*16 + g4 + r;
        int col = tn + wn + j*16 + lr;
        float v = acc[i][j][r];
        if (region < 2){
          float pv = __shfl_xor(v, 1);
          int tp = row & (TSEQ-1);
          int jj = col >> 1;
          float2 cs = csT[tp*HALF + jj];
          float res = (col & 1) ? fmaf(pv, cs.y, v*cs.x)
                                : fmaf(v, cs.x, -(pv*cs.y));
          outp[(size_t)row*KDIM + col] = f2bf(res*scale);
        } else {
          outp[(size_t)row*KDIM + col] = f2bf(v);
        }
      }
    }
  }
}

// ---------------- final GEMM: fp32 + bias (same swizzles) ----------------
__global__ __launch_bounds__(256) void gemm_out(
    const unsigned short* __restrict__ A,
    const unsigned short* __restrict__ Bw,
    float* __restrict__ outp,
    const float* __restrict__ bias){
  __shared__ __align__(16) unsigned short As[128*32];
  __shared__ __align__(16) unsigned short Bs[128*32];
  const int lin = blockIdx.y*64 + blockIdx.x;
  const int L = (lin & 7)*64 + (lin >> 3);    // bijective: 512 % 8 == 0
  const int bx = L>>3, by = L&7;              // XCD k: bx in [8k,8k+8)
  const int tm = bx*128, tn = by*128;
  const int t  = threadIdx.x;
  const int w  = t>>6, l = t&63;
  const int wm = (w>>1)*64, wn = (w&1)*64;
  const int lr = l&15, g = l>>4, g4 = (l>>4)*4;

  f32x4 acc[4][4];
  #pragma unroll
  for (int i=0;i<4;i++)
    #pragma unroll
    for (int j=0;j<4;j++) acc[i][j] = (f32x4){0.f,0.f,0.f,0.f};

  const int sr = t>>2, cc = t&3;
  const int sc = (cc ^ ((sr>>1)&3))*8;
  const unsigned short* Ag = A  + (size_t)(tm+sr)*KDIM + sc;
  const unsigned short* Bg = Bw + (size_t)(tn+sr)*KDIM + sc;
  unsigned short* Al0 = As + t*8;
  unsigned short* Al1 = As + 2048 + t*8;
  unsigned short* Bl0 = Bs + t*8;
  unsigned short* Bl1 = Bs + 2048 + t*8;

  for (int k0=0; k0<KDIM; k0+=32){
    gl_lds16(Ag + k0, Al0);
    gl_lds16(Ag + (size_t)64*KDIM + k0, Al1);
    gl_lds16(Bg + k0, Bl0);
    gl_lds16(Bg + (size_t)64*KDIM + k0, Bl1);
    __syncthreads();
    short8 af[4], bfr[4];
    #pragma unroll
    for (int i=0;i<4;i++){
      int ra = wm+i*16+lr, rb = wn+i*16+lr;
      af[i]  = *(const short8*)&As[ra*32 + (g ^ ((ra>>1)&3))*8];
      bfr[i] = *(const short8*)&Bs[rb*32 + (g ^ ((rb>>1)&3))*8];
    }
    #pragma unroll
    for (int i=0;i<4;i++)
      #pragma unroll
      for (int j=0;j<4;j++)
        acc[i][j] = mfma16(af[i], bfr[j], acc[i][j]);
    __syncthreads();
  }

  #pragma unroll
  for (int i=0;i<4;i++){
    #pragma unroll
    for (int j=0;j<4;j++){
      #pragma unroll
      for (int r=0;r<4;r++){
        int row = tm + wm + i*16 + g4 + r;
        int col = tn + wn + j*16 + lr;
        outp[(size_t)row*KDIM + col] = acc[i][j][r] + bias[col];
      }
    }
  }
}

// ---- K rearrange: kb[b*T+t][KDIM] -> per-(b,h,tile32) fragment blocks ----
// frag el (ks, l, e) = K[bT + tile*32 + (l&31)][h*64 + ks*16 + (l>>5)*8 + e]
__global__ __launch_bounds__(256) void karr(const unsigned short* __restrict__ in,
                                            unsigned short* __restrict__ out){
  const int t = threadIdx.x;
  const int tl = blockIdx.x, h = blockIdx.y, b = blockIdx.z;
  const int ks = t>>6, l = t&63, ln = l&31, h2 = l>>5;
  short8 v = *(const short8*)&in[((size_t)b*TSEQ + tl*32 + ln)*KDIM + h*HDIM + ks*16 + h2*8];
  *(short8*)&out[(((size_t)(b*NHEAD + h)*64 + tl)*2048) + t*8] = v;
}

// ---- V rearrange (transpose): vb -> per-(b,h,tile32) PV-B fragment blocks --
__global__ __launch_bounds__(256) void varr(const unsigned short* __restrict__ in,
                                            unsigned short* __restrict__ out){
  __shared__ __align__(16) unsigned short tile[32][72];
  const int t = threadIdx.x;
  const int tl = blockIdx.x, h = blockIdx.y, b = blockIdx.z;
  const int r = t>>3, c8 = (t&7)*8;
  short8 v = *(const short8*)&in[((size_t)b*TSEQ + tl*32 + r)*KDIM + h*HDIM + c8];
  *(short8*)&tile[r][c8] = v;
  __syncthreads();
  const int dt = t>>7, ks2 = (t>>6)&1;
  const int l = t&63, ln = l&31, h2 = l>>5;
  const int k0 = ks2*16 + h2*8, d = dt*32 + ln;
  unsigned short tmp[8];
  #pragma unroll
  for (int e=0;e<8;e++) tmp[e] = tile[k0+e][d];
  *(short8*)&out[(((size_t)(b*NHEAD + h)*64 + tl)*2048) + t*8] = *(const short8*)tmp;
}

// ------------- flash attention v4: depth-2 prefetch, counted vmcnt ---------
__global__ __launch_bounds__(256, 4) void flash_attn4(
    const unsigned short* __restrict__ Q,
    const unsigned short* __restrict__ Kf,
    const unsigned short* __restrict__ Vf,
    unsigned short* __restrict__ Out){
  __shared__ __align__(16) unsigned short kv[3*4096]; // [buf][K 2048el | V 2048el]
  __shared__ __align__(16) float lbuf[4][32];
  const int t = threadIdx.x;
  const int w = t>>6, l = t&63;
  const int ln = l&31, h = l>>5;
  const int by = blockIdx.y;
  const int b = by>>4, hh = by&15;
  const int q0 = blockIdx.x*128 + w*32;
  const size_t bT = (size_t)b*TSEQ;
  const int hd0 = hh*HDIM;

  short8 qf[4];
  #pragma unroll
  for (int ks=0; ks<4; ks++)
    qf[ks] = *(const short8*)&Q[(bT + q0 + ln)*KDIM + hd0 + ks*16 + h*8];

  const unsigned short* tbK = Kf + (size_t)(b*NHEAD + hh)*64*2048;
  const unsigned short* tbV = Vf + (size_t)(b*NHEAD + hh)*64*2048;

  unsigned short* pA = kv;
  unsigned short* pB = kv + 4096;
  unsigned short* pC = kv + 8192;

  auto STG = [&](int tt, unsigned short* buf){
    gl_lds16(tbK + (size_t)tt*2048 + w*512 + l*8, buf + w*512);
    gl_lds16(tbV + (size_t)tt*2048 + w*512 + l*8, buf + 2048 + w*512);
  };

  STG(0, pA);
  STG(1, pB);
  asm volatile("s_waitcnt vmcnt(2)" ::: "memory");  // tile 0 complete
  __builtin_amdgcn_s_barrier();

  f32x16 O0, O1;
  #pragma unroll
  for (int r=0;r<16;r++){ O0[r]=0.f; O1[r]=0.f; }
  float lsum = 0.f;

  for (int tt=0; tt<64; ++tt){
    if (tt < 62) STG(tt+2, pC);

    short8 kf0 = *(const short8*)&pA[0*512 + l*8];
    short8 kf1 = *(const short8*)&pA[1*512 + l*8];
    short8 kf2 = *(const short8*)&pA[2*512 + l*8];
    short8 kf3 = *(const short8*)&pA[3*512 + l*8];

    f32x16 S;
    #pragma unroll
    for (int r=0;r<16;r++) S[r]=0.f;
    __builtin_amdgcn_s_setprio(1);
    S = mfma32(kf0, qf[0], S);
    S = mfma32(kf1, qf[1], S);
    S = mfma32(kf2, qf[2], S);
    S = mfma32(kf3, qf[3], S);
    __builtin_amdgcn_s_setprio(0);

    float rs = 0.f;
    #pragma unroll
    for (int r=0;r<16;r++){ S[r] = EXP2(S[r]); rs += S[r]; }
    lsum += rs;

    unsigned int wds[8];
    #pragma unroll
    for (int i=0;i<8;i++) wds[i] = cvtpk(S[2*i], S[2*i+1]);

    unsigned int y0 = __shfl_xor(h ? wds[0] : wds[2], 32);
    unsigned int y1 = __shfl_xor(h ? wds[1] : wds[3], 32);
    unsigned int y2 = __shfl_xor(h ? wds[4] : wds[6], 32);
    unsigned int y3 = __shfl_xor(h ? wds[5] : wds[7], 32);

    u32x4 pw0 = h ? (u32x4){y0, y1, wds[2], wds[3]}
                  : (u32x4){wds[0], wds[1], y0, y1};
    u32x4 pw1 = h ? (u32x4){y2, y3, wds[6], wds[7]}
                  : (u32x4){wds[4], wds[5], y2, y3};
    short8 pa0 = *(short8*)&pw0;
    short8 pa1 = *(short8*)&pw1;

    short8 vf0 = *(const short8*)&pA[2048 + 0*512 + l*8];
    short8 vf1 = *(const short8*)&pA[2048 + 1*512 + l*8];
    short8 vf2 = *(const short8*)&pA[2048 + 2*512 + l*8];
    short8 vf3 = *(const short8*)&pA[2048 + 3*512 + l*8];
    __builtin_amdgcn_s_setprio(1);
    O0 = mfma32(pa0, vf0, O0);
    O0 = mfma32(pa1, vf1, O0);
    O1 = mfma32(pa0, vf2, O1);
    O1 = mfma32(pa1, vf3, O1);
    __builtin_amdgcn_s_setprio(0);

    if (tt < 62){
      asm volatile("s_waitcnt vmcnt(2)" ::: "memory");
    } else {
      asm volatile("s_waitcnt vmcnt(0)" ::: "memory");
    }
    __builtin_amdgcn_s_barrier();

    unsigned short* tp = pA; pA = pB; pB = pC; pC = tp;
  }

  float lfull = lsum + __shfl_xor(lsum, 32);
  float linv = 1.0f / lfull;
  if (h == 0) lbuf[w][ln] = linv;
  __syncthreads();

  #pragma unroll
  for (int gg=0; gg<4; gg++){
    f32x4 lv = *(const f32x4*)&lbuf[w][gg*8 + h*4];
    #pragma unroll
    for (int i=0; i<4; i++){
      int r = gg*4 + i;
      int row = q0 + gg*8 + h*4 + i;
      size_t base = (bT + row)*KDIM + hd0;
      Out[base + ln]      = f2bf(O0[r]*lv[i]);
      Out[base + 32 + ln] = f2bf(O1[r]*lv[i]);
    }
  }
}

extern "C" void kernel_launch(void* const* d_in, const int* in_sizes, int n_in,
                              void* d_out, int out_size, void* d_ws, size_t ws_size,
                              hipStream_t stream){
  (void)in_sizes; (void)n_in; (void)out_size; (void)ws_size;
  const float* x  = (const float*)d_in[0];
  const float* Wq = (const float*)d_in[1];
  const float* Wk = (const float*)d_in[2];
  const float* Wv = (const float*)d_in[3];
  const float* Wu = (const float*)d_in[4];
  const float* bu = (const float*)d_in[5];

  char* ws = (char*)d_ws;
  size_t off = 0;
  auto alloc = [&](size_t bytes){ void* p = ws + off; off += bytes; return p; };
  unsigned short* xb  = (unsigned short*)alloc(16777216);
  unsigned short* qb  = (unsigned short*)alloc(16777216);
  unsigned short* kb  = (unsigned short*)alloc(16777216);
  unsigned short* vb  = (unsigned short*)alloc(16777216);
  unsigned short* kfr = (unsigned short*)alloc(16777216);
  unsigned short* wqb = (unsigned short*)alloc(2097152);
  unsigned short* wkb = (unsigned short*)alloc(2097152);
  unsigned short* wvb = (unsigned short*)alloc(2097152);
  unsigned short* wub = (unsigned short*)alloc(2097152);
  float2* csT = (float2*)alloc(8388608);
  unsigned short* vfr = kb;  // alias: row-major K dead after karr
  unsigned short* att = xb;  // alias: xb dead after QKV GEMM

  cvt_bf16<<<8192, 256, 0, stream>>>(x,  xb,  2097152);
  cvt_bf16<<<1024, 256, 0, stream>>>(Wq, wqb, 262144);
  cvt_bf16<<<1024, 256, 0, stream>>>(Wk, wkb, 262144);
  cvt_bf16<<<1024, 256, 0, stream>>>(Wv, wvb, 262144);
  cvt_bf16<<<1024, 256, 0, stream>>>(Wu, wub, 262144);
  trig_init<<<4096, 256, 0, stream>>>(csT);

  gemm_qkv<<<dim3(64,24), 256, 0, stream>>>(xb, wqb, wkb, wvb,
                                            qb, kb, vb, csT);

  karr<<<dim3(64,16,4), 256, 0, stream>>>(kb, kfr);
  varr<<<dim3(64,16,4), 256, 0, stream>>>(vb, vfr);
  flash_attn4<<<dim3(16,64), 256, 0, stream>>>(qb, kfr, vfr, att);
  gemm_out<<<dim3(64,8), 256, 0, stream>>>(att, wub, (float*)d_out, bu);
}

// Round 10
// 340.778 us; speedup vs baseline: 1.0696x; 1.0696x over previous
//
#include <hip/hip_runtime.h>

#define TSEQ 2048
#define KDIM 1024
#define NHEAD 16
#define HDIM 64
#define BATCH 4
#define HALF 512

typedef __attribute__((ext_vector_type(4))) float f32x4;
typedef __attribute__((ext_vector_type(16))) float f32x16;
typedef __attribute__((ext_vector_type(8))) short short8;
typedef __attribute__((ext_vector_type(4))) unsigned short us4;
typedef __attribute__((ext_vector_type(4))) unsigned int u32x4;

#if __has_builtin(__builtin_amdgcn_exp2f)
#define EXP2(x) __builtin_amdgcn_exp2f(x)
#else
#define EXP2(x) __expf((x)*0.6931471805599453f)
#endif

__device__ __forceinline__ unsigned short f2bf(float f){
  unsigned int u = __float_as_uint(f);
  u += 0x7FFFu + ((u >> 16) & 1u);   // round-to-nearest-even
  return (unsigned short)(u >> 16);
}

__device__ __forceinline__ unsigned int cvtpk(float a, float b){
  unsigned int r;
  asm("v_cvt_pk_bf16_f32 %0, %1, %2" : "=v"(r) : "v"(a), "v"(b));
  return r;   // lo = bf16(a), hi = bf16(b)
}

__device__ __forceinline__ f32x4 mfma16(short8 a, short8 b, f32x4 c){
  return __builtin_amdgcn_mfma_f32_16x16x32_bf16(a, b, c, 0, 0, 0);
}
__device__ __forceinline__ f32x16 mfma32(short8 a, short8 b, f32x16 c){
  return __builtin_amdgcn_mfma_f32_32x32x16_bf16(a, b, c, 0, 0, 0);
}

__device__ __forceinline__ void gl_lds16(const void* g, void* l){
  __builtin_amdgcn_global_load_lds(
      (const __attribute__((address_space(1))) unsigned int*)g,
      (__attribute__((address_space(3))) unsigned int*)l, 16, 0, 0);
}

// ---------------- fp32 -> bf16 convert (vectorized) ----------------
__global__ __launch_bounds__(256) void cvt_bf16(const float* __restrict__ in,
                                                unsigned short* __restrict__ out,
                                                int n4){
  int i = blockIdx.x*256 + threadIdx.x;
  if (i >= n4) return;
  f32x4 v = ((const f32x4*)in)[i];
  us4 o;
  o[0] = f2bf(v[0]); o[1] = f2bf(v[1]); o[2] = f2bf(v[2]); o[3] = f2bf(v[3]);
  ((us4*)out)[i] = o;
}

// ------------- RoPE cos/sin table, interleaved float2 [TSEQ][HALF] --------
__global__ __launch_bounds__(256) void trig_init(float2* __restrict__ csT){
  int idx = blockIdx.x*256 + threadIdx.x;   // TSEQ*HALF total
  int t = idx >> 9;
  int j = idx & (HALF-1);
  float theta = powf(10000.0f, -(float)j * (1.0f/(float)HALF));
  float ang = (float)t * theta;
  csT[idx] = make_float2(cosf(ang), sinf(ang));
}

// -------- fused QKV GEMM, depth-2 pipelined (3 LDS buffer-sets) -----------
// grid (64, 24). Row-chunked XCD swizzle. LDS XOR-swizzle via pre-swizzled
// global source + swizzled ds_read col. Main loop: stage tile k+2, compute
// tile k, s_waitcnt vmcnt(4) (tile k+1 done, k+2 in flight), s_barrier.
__global__ __launch_bounds__(256) void gemm_qkv(
    const unsigned short* __restrict__ A,
    const unsigned short* __restrict__ Wq,
    const unsigned short* __restrict__ Wk,
    const unsigned short* __restrict__ Wv,
    unsigned short* __restrict__ Qo,
    unsigned short* __restrict__ Ko,
    unsigned short* __restrict__ Vo,
    const float2* __restrict__ csT){
  __shared__ __align__(16) unsigned short kv[3*8192]; // buf: A 4096el | B 4096el
  const int lin = blockIdx.y*64 + blockIdx.x;
  const int L = (lin & 7)*192 + (lin >> 3);   // bijective: 1536 % 8 == 0
  const int bx = L/24, by = L%24;
  const int region = by >> 3;          // 0=Q 1=K 2=V
  const int tm = bx*128, tn = (by & 7)*128;
  const unsigned short* Bw = region==0 ? Wq : (region==1 ? Wk : Wv);
  unsigned short* outp     = region==0 ? Qo : (region==1 ? Ko : Vo);
  const float scale = (region==0) ? 0.18033688011112042f : 1.0f; // 0.125*log2e

  const int t  = threadIdx.x;
  const int w  = t>>6, l = t&63;
  const int wm = (w>>1)*64, wn = (w&1)*64;
  const int lr = l&15, g = l>>4, g4 = (l>>4)*4;

  f32x4 acc[4][4];
  #pragma unroll
  for (int i=0;i<4;i++)
    #pragma unroll
    for (int j=0;j<4;j++) acc[i][j] = (f32x4){0.f,0.f,0.f,0.f};

  // staging: thread t -> LDS granule (sr, cc); source col granule cc^swz(sr)
  const int sr = t>>2, cc = t&3;
  const int sc = (cc ^ ((sr>>1)&3))*8;     // swz(sr+64)==swz(sr)
  const unsigned short* Ag = A  + (size_t)(tm+sr)*KDIM + sc;
  const unsigned short* Bg = Bw + (size_t)(tn+sr)*KDIM + sc;

  unsigned short* b0 = kv;
  unsigned short* b1 = kv + 8192;
  unsigned short* b2 = kv + 16384;

  // stage K-step k into buf: 4 gl_lds (A 2 halves, B 2 halves)
  auto STG = [&](int k, unsigned short* buf){
    const int k0 = k*32;
    gl_lds16(Ag + k0, buf + t*8);
    gl_lds16(Ag + (size_t)64*KDIM + k0, buf + 2048 + t*8);
    gl_lds16(Bg + k0, buf + 4096 + t*8);
    gl_lds16(Bg + (size_t)64*KDIM + k0, buf + 4096 + 2048 + t*8);
  };

  STG(0, b0);
  STG(1, b1);
  asm volatile("s_waitcnt vmcnt(4)" ::: "memory");  // tile 0 complete
  __builtin_amdgcn_s_barrier();

  for (int k=0; k<32; ++k){
    if (k < 30) STG(k+2, b2);

    short8 af[4], bfr[4];
    #pragma unroll
    for (int i=0;i<4;i++){
      int ra = wm+i*16+lr, rb = wn+i*16+lr;
      af[i]  = *(const short8*)&b0[ra*32 + (g ^ ((ra>>1)&3))*8];
      bfr[i] = *(const short8*)&b0[4096 + rb*32 + (g ^ ((rb>>1)&3))*8];
    }
    #pragma unroll
    for (int i=0;i<4;i++)
      #pragma unroll
      for (int j=0;j<4;j++)
        acc[i][j] = mfma16(af[i], bfr[j], acc[i][j]);

    if (k < 30){
      asm volatile("s_waitcnt vmcnt(4)" ::: "memory"); // tile k+1 done
      __builtin_amdgcn_s_barrier();
    } else if (k == 30){
      asm volatile("s_waitcnt vmcnt(0)" ::: "memory"); // tile 31 done
      __builtin_amdgcn_s_barrier();
    }
    unsigned short* tp = b0; b0 = b1; b1 = b2; b2 = tp;
  }

  #pragma unroll
  for (int i=0;i<4;i++){
    #pragma unroll
    for (int j=0;j<4;j++){
      #pragma unroll
      for (int r=0;r<4;r++){
        int row = tm + wm + i*16 + g4 + r;
        int col = tn + wn + j*16 + lr;
        float v = acc[i][j][r];
        if (region < 2){
          float pv = __shfl_xor(v, 1);
          int tp = row & (TSEQ-1);
          int jj = col >> 1;
          float2 cs = csT[tp*HALF + jj];
          float res = (col & 1) ? fmaf(pv, cs.y, v*cs.x)
                                : fmaf(v, cs.x, -(pv*cs.y));
          outp[(size_t)row*KDIM + col] = f2bf(res*scale);
        } else {
          outp[(size_t)row*KDIM + col] = f2bf(v);
        }
      }
    }
  }
}

// ------- final GEMM: fp32 + bias (2-phase control, unchanged) -------------
__global__ __launch_bounds__(256) void gemm_out(
    const unsigned short* __restrict__ A,
    const unsigned short* __restrict__ Bw,
    float* __restrict__ outp,
    const float* __restrict__ bias){
  __shared__ __align__(16) unsigned short As[128*32];
  __shared__ __align__(16) unsigned short Bs[128*32];
  const int lin = blockIdx.y*64 + blockIdx.x;
  const int L = (lin & 7)*64 + (lin >> 3);    // bijective: 512 % 8 == 0
  const int bx = L>>3, by = L&7;              // XCD k: bx in [8k,8k+8)
  const int tm = bx*128, tn = by*128;
  const int t  = threadIdx.x;
  const int w  = t>>6, l = t&63;
  const int wm = (w>>1)*64, wn = (w&1)*64;
  const int lr = l&15, g = l>>4, g4 = (l>>4)*4;

  f32x4 acc[4][4];
  #pragma unroll
  for (int i=0;i<4;i++)
    #pragma unroll
    for (int j=0;j<4;j++) acc[i][j] = (f32x4){0.f,0.f,0.f,0.f};

  const int sr = t>>2, cc = t&3;
  const int sc = (cc ^ ((sr>>1)&3))*8;
  const unsigned short* Ag = A  + (size_t)(tm+sr)*KDIM + sc;
  const unsigned short* Bg = Bw + (size_t)(tn+sr)*KDIM + sc;
  unsigned short* Al0 = As + t*8;
  unsigned short* Al1 = As + 2048 + t*8;
  unsigned short* Bl0 = Bs + t*8;
  unsigned short* Bl1 = Bs + 2048 + t*8;

  for (int k0=0; k0<KDIM; k0+=32){
    gl_lds16(Ag + k0, Al0);
    gl_lds16(Ag + (size_t)64*KDIM + k0, Al1);
    gl_lds16(Bg + k0, Bl0);
    gl_lds16(Bg + (size_t)64*KDIM + k0, Bl1);
    __syncthreads();
    short8 af[4], bfr[4];
    #pragma unroll
    for (int i=0;i<4;i++){
      int ra = wm+i*16+lr, rb = wn+i*16+lr;
      af[i]  = *(const short8*)&As[ra*32 + (g ^ ((ra>>1)&3))*8];
      bfr[i] = *(const short8*)&Bs[rb*32 + (g ^ ((rb>>1)&3))*8];
    }
    #pragma unroll
    for (int i=0;i<4;i++)
      #pragma unroll
      for (int j=0;j<4;j++)
        acc[i][j] = mfma16(af[i], bfr[j], acc[i][j]);
    __syncthreads();
  }

  #pragma unroll
  for (int i=0;i<4;i++){
    #pragma unroll
    for (int j=0;j<4;j++){
      #pragma unroll
      for (int r=0;r<4;r++){
        int row = tm + wm + i*16 + g4 + r;
        int col = tn + wn + j*16 + lr;
        outp[(size_t)row*KDIM + col] = acc[i][j][r] + bias[col];
      }
    }
  }
}

// ---- K rearrange: kb[b*T+t][KDIM] -> per-(b,h,tile32) fragment blocks ----
__global__ __launch_bounds__(256) void karr(const unsigned short* __restrict__ in,
                                            unsigned short* __restrict__ out){
  const int t = threadIdx.x;
  const int tl = blockIdx.x, h = blockIdx.y, b = blockIdx.z;
  const int ks = t>>6, l = t&63, ln = l&31, h2 = l>>5;
  short8 v = *(const short8*)&in[((size_t)b*TSEQ + tl*32 + ln)*KDIM + h*HDIM + ks*16 + h2*8];
  *(short8*)&out[(((size_t)(b*NHEAD + h)*64 + tl)*2048) + t*8] = v;
}

// ---- V rearrange (transpose): vb -> per-(b,h,tile32) PV-B fragment blocks --
__global__ __launch_bounds__(256) void varr(const unsigned short* __restrict__ in,
                                            unsigned short* __restrict__ out){
  __shared__ __align__(16) unsigned short tile[32][72];
  const int t = threadIdx.x;
  const int tl = blockIdx.x, h = blockIdx.y, b = blockIdx.z;
  const int r = t>>3, c8 = (t&7)*8;
  short8 v = *(const short8*)&in[((size_t)b*TSEQ + tl*32 + r)*KDIM + h*HDIM + c8];
  *(short8*)&tile[r][c8] = v;
  __syncthreads();
  const int dt = t>>7, ks2 = (t>>6)&1;
  const int l = t&63, ln = l&31, h2 = l>>5;
  const int k0 = ks2*16 + h2*8, d = dt*32 + ln;
  unsigned short tmp[8];
  #pragma unroll
  for (int e=0;e<8;e++) tmp[e] = tile[k0+e][d];
  *(short8*)&out[(((size_t)(b*NHEAD + h)*64 + tl)*2048) + t*8] = *(const short8*)tmp;
}

// ------------- flash attention v4: depth-2 prefetch, counted vmcnt ---------
__global__ __launch_bounds__(256, 4) void flash_attn4(
    const unsigned short* __restrict__ Q,
    const unsigned short* __restrict__ Kf,
    const unsigned short* __restrict__ Vf,
    unsigned short* __restrict__ Out){
  __shared__ __align__(16) unsigned short kv[3*4096]; // [buf][K 2048el | V 2048el]
  __shared__ __align__(16) float lbuf[4][32];
  const int t = threadIdx.x;
  const int w = t>>6, l = t&63;
  const int ln = l&31, h = l>>5;
  const int by = blockIdx.y;
  const int b = by>>4, hh = by&15;
  const int q0 = blockIdx.x*128 + w*32;
  const size_t bT = (size_t)b*TSEQ;
  const int hd0 = hh*HDIM;

  short8 qf[4];
  #pragma unroll
  for (int ks=0; ks<4; ks++)
    qf[ks] = *(const short8*)&Q[(bT + q0 + ln)*KDIM + hd0 + ks*16 + h*8];

  const unsigned short* tbK = Kf + (size_t)(b*NHEAD + hh)*64*2048;
  const unsigned short* tbV = Vf + (size_t)(b*NHEAD + hh)*64*2048;

  unsigned short* pA = kv;
  unsigned short* pB = kv + 4096;
  unsigned short* pC = kv + 8192;

  auto STG = [&](int tt, unsigned short* buf){
    gl_lds16(tbK + (size_t)tt*2048 + w*512 + l*8, buf + w*512);
    gl_lds16(tbV + (size_t)tt*2048 + w*512 + l*8, buf + 2048 + w*512);
  };

  STG(0, pA);
  STG(1, pB);
  asm volatile("s_waitcnt vmcnt(2)" ::: "memory");  // tile 0 complete
  __builtin_amdgcn_s_barrier();

  f32x16 O0, O1;
  #pragma unroll
  for (int r=0;r<16;r++){ O0[r]=0.f; O1[r]=0.f; }
  float lsum = 0.f;

  for (int tt=0; tt<64; ++tt){
    if (tt < 62) STG(tt+2, pC);

    short8 kf0 = *(const short8*)&pA[0*512 + l*8];
    short8 kf1 = *(const short8*)&pA[1*512 + l*8];
    short8 kf2 = *(const short8*)&pA[2*512 + l*8];
    short8 kf3 = *(const short8*)&pA[3*512 + l*8];

    f32x16 S;
    #pragma unroll
    for (int r=0;r<16;r++) S[r]=0.f;
    __builtin_amdgcn_s_setprio(1);
    S = mfma32(kf0, qf[0], S);
    S = mfma32(kf1, qf[1], S);
    S = mfma32(kf2, qf[2], S);
    S = mfma32(kf3, qf[3], S);
    __builtin_amdgcn_s_setprio(0);

    float rs = 0.f;
    #pragma unroll
    for (int r=0;r<16;r++){ S[r] = EXP2(S[r]); rs += S[r]; }
    lsum += rs;

    unsigned int wds[8];
    #pragma unroll
    for (int i=0;i<8;i++) wds[i] = cvtpk(S[2*i], S[2*i+1]);

    unsigned int y0 = __shfl_xor(h ? wds[0] : wds[2], 32);
    unsigned int y1 = __shfl_xor(h ? wds[1] : wds[3], 32);
    unsigned int y2 = __shfl_xor(h ? wds[4] : wds[6], 32);
    unsigned int y3 = __shfl_xor(h ? wds[5] : wds[7], 32);

    u32x4 pw0 = h ? (u32x4){y0, y1, wds[2], wds[3]}
                  : (u32x4){wds[0], wds[1], y0, y1};
    u32x4 pw1 = h ? (u32x4){y2, y3, wds[6], wds[7]}
                  : (u32x4){wds[4], wds[5], y2, y3};
    short8 pa0 = *(short8*)&pw0;
    short8 pa1 = *(short8*)&pw1;

    short8 vf0 = *(const short8*)&pA[2048 + 0*512 + l*8];
    short8 vf1 = *(const short8*)&pA[2048 + 1*512 + l*8];
    short8 vf2 = *(const short8*)&pA[2048 + 2*512 + l*8];
    short8 vf3 = *(const short8*)&pA[2048 + 3*512 + l*8];
    __builtin_amdgcn_s_setprio(1);
    O0 = mfma32(pa0, vf0, O0);
    O0 = mfma32(pa1, vf1, O0);
    O1 = mfma32(pa0, vf2, O1);
    O1 = mfma32(pa1, vf3, O1);
    __builtin_amdgcn_s_setprio(0);

    if (tt < 62){
      asm volatile("s_waitcnt vmcnt(2)" ::: "memory");
    } else {
      asm volatile("s_waitcnt vmcnt(0)" ::: "memory");
    }
    __builtin_amdgcn_s_barrier();

    unsigned short* tp = pA; pA = pB; pB = pC; pC = tp;
  }

  float lfull = lsum + __shfl_xor(lsum, 32);
  float linv = 1.0f / lfull;
  if (h == 0) lbuf[w][ln] = linv;
  __syncthreads();

  #pragma unroll
  for (int gg=0; gg<4; gg++){
    f32x4 lv = *(const f32x4*)&lbuf[w][gg*8 + h*4];
    #pragma unroll
    for (int i=0; i<4; i++){
      int r = gg*4 + i;
      int row = q0 + gg*8 + h*4 + i;
      size_t base = (bT + row)*KDIM + hd0;
      Out[base + ln]      = f2bf(O0[r]*lv[i]);
      Out[base + 32 + ln] = f2bf(O1[r]*lv[i]);
    }
  }
}

extern "C" void kernel_launch(void* const* d_in, const int* in_sizes, int n_in,
                              void* d_out, int out_size, void* d_ws, size_t ws_size,
                              hipStream_t stream){
  (void)in_sizes; (void)n_in; (void)out_size; (void)ws_size;
  const float* x  = (const float*)d_in[0];
  const float* Wq = (const float*)d_in[1];
  const float* Wk = (const float*)d_in[2];
  const float* Wv = (const float*)d_in[3];
  const float* Wu = (const float*)d_in[4];
  const float* bu = (const float*)d_in[5];

  char* ws = (char*)d_ws;
  size_t off = 0;
  auto alloc = [&](size_t bytes){ void* p = ws + off; off += bytes; return p; };
  unsigned short* xb  = (unsigned short*)alloc(16777216);
  unsigned short* qb  = (unsigned short*)alloc(16777216);
  unsigned short* kb  = (unsigned short*)alloc(16777216);
  unsigned short* vb  = (unsigned short*)alloc(16777216);
  unsigned short* kfr = (unsigned short*)alloc(16777216);
  unsigned short* wqb = (unsigned short*)alloc(2097152);
  unsigned short* wkb = (unsigned short*)alloc(2097152);
  unsigned short* wvb = (unsigned short*)alloc(2097152);
  unsigned short* wub = (unsigned short*)alloc(2097152);
  float2* csT = (float2*)alloc(8388608);
  unsigned short* vfr = kb;  // alias: row-major K dead after karr
  unsigned short* att = xb;  // alias: xb dead after QKV GEMM

  cvt_bf16<<<8192, 256, 0, stream>>>(x,  xb,  2097152);
  cvt_bf16<<<1024, 256, 0, stream>>>(Wq, wqb, 262144);
  cvt_bf16<<<1024, 256, 0, stream>>>(Wk, wkb, 262144);
  cvt_bf16<<<1024, 256, 0, stream>>>(Wv, wvb, 262144);
  cvt_bf16<<<1024, 256, 0, stream>>>(Wu, wub, 262144);
  trig_init<<<4096, 256, 0, stream>>>(csT);

  gemm_qkv<<<dim3(64,24), 256, 0, stream>>>(xb, wqb, wkb, wvb,
                                            qb, kb, vb, csT);

  karr<<<dim3(64,16,4), 256, 0, stream>>>(kb, kfr);
  varr<<<dim3(64,16,4), 256, 0, stream>>>(vb, vfr);
  flash_attn4<<<dim3(16,64), 256, 0, stream>>>(qb, kfr, vfr, att);
  gemm_out<<<dim3(64,8), 256, 0, stream>>>(att, wub, (float*)d_out, bu);
}